// Round 3
// baseline (6092.698 us; speedup 1.0000x reference)
//
#include <hip/hip_runtime.h>
#include <stdint.h>

typedef uint32_t u32; typedef uint16_t u16;
typedef __attribute__((ext_vector_type(8))) __bf16 bf16x8;
typedef __attribute__((ext_vector_type(4))) float f32x4;
typedef __attribute__((ext_vector_type(2))) u32 u32x2;
typedef __attribute__((ext_vector_type(4))) u32 u32x4;

#define Vv 50000
#define Ee 256
#define Hh 256
#define Gg 768
#define Bb 64
#define Tt 2048

__device__ __forceinline__ u16 f2bf(float f) {
  u32 x = __builtin_bit_cast(u32, f);
  return (u16)((x + 0x7FFFu + ((x >> 16) & 1u)) >> 16);
}
__device__ __forceinline__ float bf2f(u16 b) {
  u32 x = ((u32)b) << 16;
  return __builtin_bit_cast(float, x);
}
__device__ __forceinline__ u32 pack2(float a, float b) {
  return (u32)f2bf(a) | ((u32)f2bf(b) << 16);
}
__device__ __forceinline__ float sigm(float x) {
  float e = __builtin_amdgcn_exp2f(-1.44269504089f * x);
  return __builtin_amdgcn_rcpf(1.0f + e);
}
__device__ __forceinline__ float tanh_fast(float x) {
  float e = __builtin_amdgcn_exp2f(2.88539008178f * x);
  return 1.0f - 2.0f * __builtin_amdgcn_rcpf(e + 1.0f);
}
__device__ __forceinline__ float bfx(u32x2 v, int q) {  // q static after unroll
  u32 word = (q & 2) ? v[1] : v[0];
  u16 h = (q & 1) ? (u16)(word >> 16) : (u16)(word & 0xffffu);
  return bf2f(h);
}
// barrier that does NOT drain vmcnt: LDS ordering only (T4 / HK pattern).
__device__ __forceinline__ void block_sync_lds() {
  asm volatile("s_waitcnt lgkmcnt(0)" ::: "memory");
  __builtin_amdgcn_s_barrier();
  asm volatile("" ::: "memory");
}

// ---------------- K0: bias row (row Vv) of both P tables ----------------
__global__ void k0_bias(const float* __restrict__ bih_f, const float* __restrict__ bhh_f,
                        const float* __restrict__ bih_b, const float* __restrict__ bhh_b,
                        u16* __restrict__ Pf, u16* __restrict__ Pb) {
  int c = threadIdx.x + blockIdx.x * 256;
  if (c < Gg) {
    float bf_ = bih_f[c] + (c < 512 ? bhh_f[c] : 0.f);
    float bb_ = bih_b[c] + (c < 512 ? bhh_b[c] : 0.f);
    Pf[(size_t)Vv * Gg + c] = f2bf(bf_);
    Pb[(size_t)Vv * Gg + c] = f2bf(bb_);
  }
}

// ---------------- K1: P'[v,g] = emb[v]@W_ih^T + bias (bf16) ----------------
// grid (391, 2): block owns 128 emb rows; A converted to LDS frags ONCE,
// then loops all 12 n-blocks (W staged per n-block). Frag-unit LDS layout
// [kt][row][rq] -> all wave reads are 64 consecutive 16B units (no conflicts).
__global__ __launch_bounds__(256) void k1_proj(
    const float* __restrict__ emb, const float* __restrict__ Wih_f,
    const float* __restrict__ Wih_b,
    const float* __restrict__ bih_f, const float* __restrict__ bhh_f,
    const float* __restrict__ bih_b, const float* __restrict__ bhh_b,
    u16* __restrict__ Pf, u16* __restrict__ Pb)
{
  const int t = threadIdx.x, w = t >> 6, l = t & 63;
  const int cl = l & 15, rq = l >> 4;
  const int m0 = blockIdx.x * 128;
  const int dir = blockIdx.y;
  const float* Wih = dir ? Wih_b : Wih_f;
  const float* bih = dir ? bih_b : bih_f;
  const float* bhh = dir ? bhh_b : bhh_f;
  u16* Pd = dir ? Pb : Pf;

  __shared__ __align__(16) u16 As[4096 * 8];   // 64 KB: [kt 0..7][row 0..127][rq 0..3] 16B units
  __shared__ __align__(16) u16 Bs[2048 * 8];   // 32 KB: [kt 0..7][wrow 0..63][rq 0..3]

  // ---- stage A (emb tile -> bf16 frags), once ----
  for (int i = t; i < 4096; i += 256) {
    const int kt = i >> 9, rem = i & 511, row = rem >> 2, rqv = rem & 3;
    const int gm = m0 + row;
    float4 a0 = {0.f,0.f,0.f,0.f}, a1 = {0.f,0.f,0.f,0.f};
    if (gm < Vv) {
      const float* src = emb + (size_t)gm * Ee + kt * 32 + rqv * 8;
      a0 = *(const float4*)src;
      a1 = *(const float4*)(src + 4);
    }
    u32x4 uv = { pack2(a0.x, a0.y), pack2(a0.z, a0.w),
                 pack2(a1.x, a1.y), pack2(a1.z, a1.w) };
    *(u32x4*)(As + (size_t)i * 8) = uv;
  }
  __syncthreads();

  for (int nb = 0; nb < 12; ++nb) {
    // ---- stage B (64 W rows) ----
    for (int i = t; i < 2048; i += 256) {
      const int kt = i >> 8, rem = i & 255, r2 = rem >> 2, rqv = rem & 3;
      const float* src = Wih + (size_t)(nb * 64 + r2) * Ee + kt * 32 + rqv * 8;
      const float4 b0 = *(const float4*)src;
      const float4 b1 = *(const float4*)(src + 4);
      u32x4 uv = { pack2(b0.x, b0.y), pack2(b0.z, b0.w),
                   pack2(b1.x, b1.y), pack2(b1.z, b1.w) };
      *(u32x4*)(Bs + (size_t)i * 8) = uv;
    }
    __syncthreads();

    f32x4 zero4 = {0.f, 0.f, 0.f, 0.f};
    f32x4 acc[2][4];
#pragma unroll
    for (int mt = 0; mt < 2; ++mt)
#pragma unroll
      for (int nt = 0; nt < 4; ++nt) acc[mt][nt] = zero4;

#pragma unroll
    for (int kt = 0; kt < 8; ++kt) {
      bf16x8 af[2], bfr[4];
#pragma unroll
      for (int mt = 0; mt < 2; ++mt)
        af[mt] = *(const bf16x8*)(As + ((size_t)kt * 512 + (w * 32 + mt * 16 + cl) * 4 + rq) * 8);
#pragma unroll
      for (int nt = 0; nt < 4; ++nt)
        bfr[nt] = *(const bf16x8*)(Bs + ((size_t)kt * 256 + (nt * 16 + cl) * 4 + rq) * 8);
#pragma unroll
      for (int mt = 0; mt < 2; ++mt)
#pragma unroll
        for (int nt = 0; nt < 4; ++nt)
          acc[mt][nt] = __builtin_amdgcn_mfma_f32_16x16x32_bf16(af[mt], bfr[nt], acc[mt][nt], 0, 0, 0);
    }

#pragma unroll
    for (int mt = 0; mt < 2; ++mt)
#pragma unroll
      for (int nt = 0; nt < 4; ++nt) {
        const int col = nb * 64 + nt * 16 + cl;
        float bias = bih[col];
        if (col < 512) bias += bhh[col];
#pragma unroll
        for (int q = 0; q < 4; ++q) {
          const int row = m0 + w * 32 + mt * 16 + rq * 4 + q;
          if (row < Vv) Pd[(size_t)row * Gg + col] = f2bf(acc[mt][nt][q] + bias);
        }
      }
    __syncthreads();   // before Bs overwrite
  }
}

// ---------------- K2: bidirectional GRU recurrence ----------------
// 8 blocks (dir = blk>>2, 16 batch rows each), 512 threads (8 waves), 1 WG/CU.
// W_hh persistent in 192 regs/lane; h double-buffered in LDS as 16B fragments
// [kb][row][rq^] (conflict-free reads, 2-way writes); raw s_barrier (lgkm only)
// so the gi gather stays in flight across the barrier (latency hidden by MFMA).
__global__ __launch_bounds__(512, 2) void k2_rec(
    const int* __restrict__ seqs, const int* __restrict__ lens,
    const float* __restrict__ Whh_f, const float* __restrict__ Whh_b,
    const float* __restrict__ bhh_f, const float* __restrict__ bhh_b,
    const u16* __restrict__ Pf, const u16* __restrict__ Pb,
    float* __restrict__ rep)
{
  const int tid = threadIdx.x, w = tid >> 6, l = tid & 63;
  const int cl = l & 15, rq = l >> 4;
  const int dir = (int)blockIdx.x >> 2;
  const int b0 = ((int)blockIdx.x & 3) * 16;

  const float* Whh = dir ? Whh_b : Whh_f;
  const float* bhh = dir ? bhh_b : bhh_f;
  const u16* P = dir ? Pb : Pf;

  __shared__ __align__(16) u16 h_lds[8192];   // 16 KB: 2 bufs x [kb 0..7][row 0..15][j 0..3] 16B units

  // ---- W_hh A-fragments, persistent in registers ----
  bf16x8 wfrag[3][2][8];
#pragma unroll
  for (int g = 0; g < 3; ++g)
#pragma unroll
    for (int bi = 0; bi < 2; ++bi) {
      const int c = g * 256 + (2 * w + bi) * 16 + cl;
      const float* wr = Whh + (size_t)c * Hh;
#pragma unroll
      for (int kb = 0; kb < 8; ++kb) {
        const int k0 = kb * 32 + rq * 8;
        const float4 f0 = *(const float4*)(wr + k0);
        const float4 f1 = *(const float4*)(wr + k0 + 4);
        u32x4 uv = { pack2(f0.x, f0.y), pack2(f0.z, f0.w),
                     pack2(f1.x, f1.y), pack2(f1.z, f1.w) };
        wfrag[g][bi][kb] = __builtin_bit_cast(bf16x8, uv);
      }
    }

  // acc_n init source: b_hh_n at cols (2w+bi)*16 + rq*4 .. +3 (L1-resident, reloaded per step)
  const float* bhhn0 = bhh + 512 + w * 32 + rq * 4;
  const float* bhhn1 = bhhn0 + 16;

  float hprev[2][4];
#pragma unroll
  for (int bi = 0; bi < 2; ++bi)
#pragma unroll
    for (int q = 0; q < 4; ++q) hprev[bi][q] = 0.f;

  const int myrow = b0 + cl;
  const int mylen = lens[myrow];
  const int* myseq = seqs + (size_t)myrow * Tt;
  const int vthr = Tt - mylen;

  for (int i = tid; i < 4096; i += 512) ((u32*)h_lds)[i] = 0;

  // lane LDS byte offsets
  const int xk = (cl >> 1);                                    // XOR key
  const int rdoff = cl * 64 + (((rq + xk) & 3) << 4);          // + kb*1024 + buf
  const int wr0 = w * 1024 + cl * 64 + ((((rq >> 1) + xk) & 3) << 4) + (rq & 1) * 8;
  const int wr1 = w * 1024 + cl * 64 + ((((rq >> 1) + 2 + xk) & 3) << 4) + (rq & 1) * 8;

  const int colb0 = w * 32 + rq * 4;     // u16 offset of bi=0 gi chunk within a P row

  // ---- prologue: gi(0) into regs; token for step 1 ----
  u32x2 gi0[3], gi1[3];
  {
    const int tk = myseq[dir ? (Tt - 1) : 0];
    const int valid = dir ? (0 < mylen) : (0 >= vthr);
    const u32 off = (valid ? (u32)tk : (u32)Vv) * (u32)(Gg * 2);
    const u16* pr = (const u16*)((const char*)P + off) + colb0;
#pragma unroll
    for (int g = 0; g < 3; ++g) {
      gi0[g] = *(const u32x2*)(pr + g * 256);
      gi1[g] = *(const u32x2*)(pr + g * 256 + 16);
    }
  }
  int tok1 = myseq[dir ? (Tt - 2) : 1];
  block_sync_lds();

  int bb = 0;
#pragma unroll 1
  for (int s = 0; s < Tt; ++s) {
    const char* hb = (const char*)h_lds + bb;
    char* hn = (char*)h_lds + (bb ^ 8192);

    f32x4 zero4 = {0.f, 0.f, 0.f, 0.f};
    f32x4 ar0 = zero4, az0 = zero4, ar1 = zero4, az1 = zero4;
    f32x4 an0 = *(const f32x4*)bhhn0;    // b_hh_n folded into acc init
    f32x4 an1 = *(const f32x4*)bhhn1;

    // ---- gh^T = W_hh · h^T ----
#pragma unroll
    for (int kb = 0; kb < 8; ++kb) {
      const bf16x8 hf = *(const bf16x8*)(hb + kb * 1024 + rdoff);
      ar0 = __builtin_amdgcn_mfma_f32_16x16x32_bf16(wfrag[0][0][kb], hf, ar0, 0, 0, 0);
      az0 = __builtin_amdgcn_mfma_f32_16x16x32_bf16(wfrag[1][0][kb], hf, az0, 0, 0, 0);
      an0 = __builtin_amdgcn_mfma_f32_16x16x32_bf16(wfrag[2][0][kb], hf, an0, 0, 0, 0);
      ar1 = __builtin_amdgcn_mfma_f32_16x16x32_bf16(wfrag[0][1][kb], hf, ar1, 0, 0, 0);
      az1 = __builtin_amdgcn_mfma_f32_16x16x32_bf16(wfrag[1][1][kb], hf, az1, 0, 0, 0);
      an1 = __builtin_amdgcn_mfma_f32_16x16x32_bf16(wfrag[2][1][kb], hf, an1, 0, 0, 0);
    }

    // token for s+2
    int tok2 = tok1;
    if (s + 2 < Tt) tok2 = myseq[dir ? (Tt - 3 - s) : (s + 2)];

    // gi row pointer for s+1 (always computed; dead on last iter)
    const int validn = dir ? (s + 1 < mylen) : (s + 1 >= vthr);
    const u32 offn = (validn ? (u32)tok1 : (u32)Vv) * (u32)(Gg * 2);
    const u16* prn = (const u16*)((const char*)P + offn) + colb0;

    // ---- gates + h' + gi reload (bi = 0, then 1) ----
#define GATES(BI, GIS, AR, AZ, AN, WRO, PRADD)                                   \
    {                                                                            \
      float hq[4];                                                               \
      _Pragma("unroll")                                                          \
      for (int q = 0; q < 4; ++q) {                                              \
        const float ir = bfx(GIS[0], q);                                         \
        const float iz = bfx(GIS[1], q);                                         \
        const float in_ = bfx(GIS[2], q);                                        \
        const float r = sigm(ir + AR[q]);                                        \
        const float z = sigm(iz + AZ[q]);                                        \
        const float n = tanh_fast(fmaf(r, AN[q], in_));                          \
        const float hv = fmaf(z, hprev[BI][q] - n, n);                           \
        hprev[BI][q] = hv;                                                       \
        hq[q] = hv;                                                              \
      }                                                                          \
      u32 p0, p1;                                                                \
      asm("v_cvt_pk_bf16_f32 %0, %1, %2" : "=v"(p0) : "v"(hq[0]), "v"(hq[1]));   \
      asm("v_cvt_pk_bf16_f32 %0, %1, %2" : "=v"(p1) : "v"(hq[2]), "v"(hq[3]));   \
      u32x2 hw = {p0, p1};                                                       \
      *(u32x2*)(hn + (bb ^ 8192) * 0 + WRO) = hw;                                \
      _Pragma("unroll")                                                          \
      for (int g = 0; g < 3; ++g) GIS[g] = *(const u32x2*)(prn + g * 256 + PRADD); \
    }

    GATES(0, gi0, ar0, az0, an0, wr0, 0)
    GATES(1, gi1, ar1, az1, an1, wr1, 16)
#undef GATES

    tok1 = tok2;
    bb ^= 8192;
    block_sync_lds();
  }

  // ---- final h -> rep ----
#pragma unroll
  for (int bi = 0; bi < 2; ++bi)
#pragma unroll
    for (int q = 0; q < 4; ++q) {
      const int col = w * 32 + bi * 16 + rq * 4 + q;
      rep[(size_t)(b0 + cl) * (2 * Hh) + dir * Hh + col] = hprev[bi][q];
    }
}

// ---------------- K3a: h1 = relu(rep @ W1^T + b1) ----------------
__global__ __launch_bounds__(256) void k3a(
    const float* __restrict__ rep, const float* __restrict__ W1,
    const float* __restrict__ b1, float* __restrict__ h1)
{
  __shared__ float rl[512];
  const int b = blockIdx.x, t = threadIdx.x;
  rl[t] = rep[(size_t)b * 512 + t];
  rl[t + 256] = rep[(size_t)b * 512 + 256 + t];
  __syncthreads();
#pragma unroll
  for (int oo = 0; oo < 2; ++oo) {
    const int o = t + oo * 256;
    const float4* wr = (const float4*)(W1 + (size_t)o * 512);
    const float4* rr = (const float4*)rl;
    float acc = 0.f;
#pragma unroll 8
    for (int k = 0; k < 128; ++k) {
      const float4 wv = wr[k], rv = rr[k];
      acc += wv.x * rv.x + wv.y * rv.y + wv.z * rv.z + wv.w * rv.w;
    }
    h1[(size_t)b * 512 + o] = fmaxf(acc + b1[o], 0.f);
  }
}

// ---------------- K3b: out = softmax(h1 @ W2^T + b2) ----------------
__global__ __launch_bounds__(320) void k3b(
    const float* __restrict__ h1, const float* __restrict__ W2,
    const float* __restrict__ b2, float* __restrict__ out)
{
  __shared__ float lg[64 * 5];
  const int t = threadIdx.x;      // 320 = 5 classes x 64 batch
  const int c = t >> 6, b = t & 63;
  const float4* hr = (const float4*)(h1 + (size_t)b * 512);
  const float4* wr = (const float4*)(W2 + (size_t)c * 512);
  float acc = 0.f;
#pragma unroll 8
  for (int k = 0; k < 128; ++k) {
    const float4 hv = hr[k], wv = wr[k];
    acc += hv.x * wv.x + hv.y * wv.y + hv.z * wv.z + hv.w * wv.w;
  }
  lg[b * 5 + c] = acc + b2[c];
  __syncthreads();
  if (t < 64) {
    float v[5];
#pragma unroll
    for (int i = 0; i < 5; ++i) v[i] = lg[t * 5 + i];
    float m = v[0];
#pragma unroll
    for (int i = 1; i < 5; ++i) m = fmaxf(m, v[i]);
    float ssum = 0.f;
#pragma unroll
    for (int i = 0; i < 5; ++i) {
      v[i] = __builtin_amdgcn_exp2f(1.44269504089f * (v[i] - m));
      ssum += v[i];
    }
    const float inv = 1.0f / ssum;
#pragma unroll
    for (int i = 0; i < 5; ++i) out[t * 5 + i] = v[i] * inv;
  }
}

extern "C" void kernel_launch(void* const* d_in, const int* in_sizes, int n_in,
                              void* d_out, int out_size, void* d_ws, size_t ws_size,
                              hipStream_t stream) {
  const int* seqs = (const int*)d_in[0];
  const int* lens = (const int*)d_in[1];
  const float* emb = (const float*)d_in[2];
  const float* Wih_f = (const float*)d_in[3];
  const float* Whh_f = (const float*)d_in[4];
  const float* bih_f = (const float*)d_in[5];
  const float* bhh_f = (const float*)d_in[6];
  const float* Wih_b = (const float*)d_in[7];
  const float* Whh_b = (const float*)d_in[8];
  const float* bih_b = (const float*)d_in[9];
  const float* bhh_b = (const float*)d_in[10];
  const float* W1 = (const float*)d_in[11];
  const float* b1 = (const float*)d_in[12];
  const float* W2 = (const float*)d_in[13];
  const float* b2 = (const float*)d_in[14];
  float* out = (float*)d_out;

  char* ws = (char*)d_ws;
  const size_t PSZ = (size_t)(Vv + 1) * Gg * 2;   // 76,801,536 B per direction
  u16* Pf = (u16*)ws;
  u16* Pb = (u16*)(ws + PSZ);
  float* rep = (float*)(ws + 2 * PSZ);            // 64*512*4
  float* h1 = (float*)(ws + 2 * PSZ + 131072);

  hipLaunchKernelGGL(k0_bias, dim3(3), dim3(256), 0, stream,
                     bih_f, bhh_f, bih_b, bhh_b, Pf, Pb);
  hipLaunchKernelGGL(k1_proj, dim3(391, 2), dim3(256), 0, stream,
                     emb, Wih_f, Wih_b, bih_f, bhh_f, bih_b, bhh_b, Pf, Pb);
  hipLaunchKernelGGL(k2_rec, dim3(8), dim3(512), 0, stream,
                     seqs, lens, Whh_f, Whh_b, bhh_f, bhh_b, Pf, Pb, rep);
  hipLaunchKernelGGL(k3a, dim3(64), dim3(256), 0, stream, rep, W1, b1, h1);
  hipLaunchKernelGGL(k3b, dim3(1), dim3(320), 0, stream, h1, W2, b2, out);
}

// Round 4
// 5898.301 us; speedup vs baseline: 1.0330x; 1.0330x over previous
//
#include <hip/hip_runtime.h>
#include <stdint.h>

typedef uint32_t u32; typedef uint16_t u16;
typedef __attribute__((ext_vector_type(8))) __bf16 bf16x8;
typedef __attribute__((ext_vector_type(4))) float f32x4;
typedef __attribute__((ext_vector_type(2))) u32 u32x2;
typedef __attribute__((ext_vector_type(4))) u32 u32x4;

#define Vv 50000
#define Ee 256
#define Hh 256
#define Gg 768
#define Bb 64
#define Tt 2048

__device__ __forceinline__ u16 f2bf(float f) {
  u32 x = __builtin_bit_cast(u32, f);
  return (u16)((x + 0x7FFFu + ((x >> 16) & 1u)) >> 16);
}
__device__ __forceinline__ float bf2f(u16 b) {
  u32 x = ((u32)b) << 16;
  return __builtin_bit_cast(float, x);
}
__device__ __forceinline__ u32 pack2(float a, float b) {
  return (u32)f2bf(a) | ((u32)f2bf(b) << 16);
}
__device__ __forceinline__ float sigm(float x) {
  float e = __builtin_amdgcn_exp2f(-1.44269504089f * x);
  return __builtin_amdgcn_rcpf(1.0f + e);
}
__device__ __forceinline__ float tanh_fast(float x) {
  float e = __builtin_amdgcn_exp2f(2.88539008178f * x);
  return 1.0f - 2.0f * __builtin_amdgcn_rcpf(e + 1.0f);
}
// 1-op/value bf16 pair extraction
__device__ __forceinline__ float bflo(u32 v) { return __builtin_bit_cast(float, v << 16); }
__device__ __forceinline__ float bfhi(u32 v) { return __builtin_bit_cast(float, v & 0xffff0000u); }

// barrier that does NOT drain vmcnt: LDS ordering only (T4 / HK pattern).
__device__ __forceinline__ void block_sync_lds() {
  asm volatile("s_waitcnt lgkmcnt(0)" ::: "memory");
  __builtin_amdgcn_s_barrier();
  asm volatile("" ::: "memory");
}

// ---------------- K0: bias row (row Vv) of both P tables ----------------
__global__ void k0_bias(const float* __restrict__ bih_f, const float* __restrict__ bhh_f,
                        const float* __restrict__ bih_b, const float* __restrict__ bhh_b,
                        u16* __restrict__ Pf, u16* __restrict__ Pb) {
  int c = threadIdx.x + blockIdx.x * 256;
  if (c < Gg) {
    float bf_ = bih_f[c] + (c < 512 ? bhh_f[c] : 0.f);
    float bb_ = bih_b[c] + (c < 512 ? bhh_b[c] : 0.f);
    Pf[(size_t)Vv * Gg + c] = f2bf(bf_);
    Pb[(size_t)Vv * Gg + c] = f2bf(bb_);
  }
}

// ---------------- K1: P'[v,g] = emb[v]@W_ih^T + bias (bf16) ----------------
// grid (391, 2, 2): block owns 128 emb rows x 6 n-blocks (half = blockIdx.z).
__global__ __launch_bounds__(256) void k1_proj(
    const float* __restrict__ emb, const float* __restrict__ Wih_f,
    const float* __restrict__ Wih_b,
    const float* __restrict__ bih_f, const float* __restrict__ bhh_f,
    const float* __restrict__ bih_b, const float* __restrict__ bhh_b,
    u16* __restrict__ Pf, u16* __restrict__ Pb)
{
  const int t = threadIdx.x, w = t >> 6, l = t & 63;
  const int cl = l & 15, rq = l >> 4;
  const int m0 = blockIdx.x * 128;
  const int dir = blockIdx.y;
  const int nbase = blockIdx.z * 6;
  const float* Wih = dir ? Wih_b : Wih_f;
  const float* bih = dir ? bih_b : bih_f;
  const float* bhh = dir ? bhh_b : bhh_f;
  u16* Pd = dir ? Pb : Pf;

  __shared__ __align__(16) u16 As[4096 * 8];   // 64 KB: [kt][row][rq] 16B units
  __shared__ __align__(16) u16 Bs[2048 * 8];   // 32 KB

  for (int i = t; i < 4096; i += 256) {
    const int kt = i >> 9, rem = i & 511, row = rem >> 2, rqv = rem & 3;
    const int gm = m0 + row;
    float4 a0 = {0.f,0.f,0.f,0.f}, a1 = {0.f,0.f,0.f,0.f};
    if (gm < Vv) {
      const float* src = emb + (size_t)gm * Ee + kt * 32 + rqv * 8;
      a0 = *(const float4*)src;
      a1 = *(const float4*)(src + 4);
    }
    u32x4 uv = { pack2(a0.x, a0.y), pack2(a0.z, a0.w),
                 pack2(a1.x, a1.y), pack2(a1.z, a1.w) };
    *(u32x4*)(As + (size_t)i * 8) = uv;
  }
  __syncthreads();

  for (int nbo = 0; nbo < 6; ++nbo) {
    const int nb = nbase + nbo;
    for (int i = t; i < 2048; i += 256) {
      const int kt = i >> 8, rem = i & 255, r2 = rem >> 2, rqv = rem & 3;
      const float* src = Wih + (size_t)(nb * 64 + r2) * Ee + kt * 32 + rqv * 8;
      const float4 b0 = *(const float4*)src;
      const float4 b1 = *(const float4*)(src + 4);
      u32x4 uv = { pack2(b0.x, b0.y), pack2(b0.z, b0.w),
                   pack2(b1.x, b1.y), pack2(b1.z, b1.w) };
      *(u32x4*)(Bs + (size_t)i * 8) = uv;
    }
    __syncthreads();

    f32x4 zero4 = {0.f, 0.f, 0.f, 0.f};
    f32x4 acc[2][4];
#pragma unroll
    for (int mt = 0; mt < 2; ++mt)
#pragma unroll
      for (int nt = 0; nt < 4; ++nt) acc[mt][nt] = zero4;

#pragma unroll
    for (int kt = 0; kt < 8; ++kt) {
      bf16x8 af[2], bfr[4];
#pragma unroll
      for (int mt = 0; mt < 2; ++mt)
        af[mt] = *(const bf16x8*)(As + ((size_t)kt * 512 + (w * 32 + mt * 16 + cl) * 4 + rq) * 8);
#pragma unroll
      for (int nt = 0; nt < 4; ++nt)
        bfr[nt] = *(const bf16x8*)(Bs + ((size_t)kt * 256 + (nt * 16 + cl) * 4 + rq) * 8);
#pragma unroll
      for (int mt = 0; mt < 2; ++mt)
#pragma unroll
        for (int nt = 0; nt < 4; ++nt)
          acc[mt][nt] = __builtin_amdgcn_mfma_f32_16x16x32_bf16(af[mt], bfr[nt], acc[mt][nt], 0, 0, 0);
    }

#pragma unroll
    for (int mt = 0; mt < 2; ++mt)
#pragma unroll
      for (int nt = 0; nt < 4; ++nt) {
        const int col = nb * 64 + nt * 16 + cl;
        float bias = bih[col];
        if (col < 512) bias += bhh[col];
#pragma unroll
        for (int q = 0; q < 4; ++q) {
          const int row = m0 + w * 32 + mt * 16 + rq * 4 + q;
          if (row < Vv) Pd[(size_t)row * Gg + col] = f2bf(acc[mt][nt][q] + bias);
        }
      }
    __syncthreads();
  }
}

// ---------------- K2: bidirectional GRU recurrence ----------------
// 8 blocks (dir = blk>>2, 16 batch rows), 512 threads (8 waves), 1 WG/CU.
// W_hh persistent in 192 regs/lane; h double-buffered in LDS as XOR-swizzled
// 16B fragments (conflict-free); lgkm-only barrier so gi gathers stay in
// flight across it. MFMA phase has ZERO VMEM dependencies (bhhn in regs);
// first vmcnt wait is in GATES, ~a full MFMA phase after the gi issue.
__global__ __launch_bounds__(512, 2) void k2_rec(
    const int* __restrict__ seqs, const int* __restrict__ lens,
    const float* __restrict__ Whh_f, const float* __restrict__ Whh_b,
    const float* __restrict__ bhh_f, const float* __restrict__ bhh_b,
    const u16* __restrict__ Pf, const u16* __restrict__ Pb,
    float* __restrict__ rep)
{
  const int tid = threadIdx.x, w = tid >> 6, l = tid & 63;
  const int cl = l & 15, rq = l >> 4;
  const int dir = (int)blockIdx.x >> 2;
  const int b0 = ((int)blockIdx.x & 3) * 16;

  const float* Whh = dir ? Whh_b : Whh_f;
  const float* bhh = dir ? bhh_b : bhh_f;
  const u16* P = dir ? Pb : Pf;

  __shared__ __align__(16) u16 h_lds[8192];   // 2 x 8 KB: [kb][row][j^] 16B units

  // ---- W_hh A-fragments, persistent ----
  bf16x8 wfrag[3][2][8];
#pragma unroll
  for (int g = 0; g < 3; ++g)
#pragma unroll
    for (int bi = 0; bi < 2; ++bi) {
      const int c = g * 256 + (2 * w + bi) * 16 + cl;
      const float* wr = Whh + (size_t)c * Hh;
#pragma unroll
      for (int kb = 0; kb < 8; ++kb) {
        const int k0 = kb * 32 + rq * 8;
        const float4 f0 = *(const float4*)(wr + k0);
        const float4 f1 = *(const float4*)(wr + k0 + 4);
        u32x4 uv = { pack2(f0.x, f0.y), pack2(f0.z, f0.w),
                     pack2(f1.x, f1.y), pack2(f1.z, f1.w) };
        wfrag[g][bi][kb] = __builtin_bit_cast(bf16x8, uv);
      }
    }

  // b_hh_n in registers (acc_n init source) — NOT reloaded per step.
  f32x4 bhn0 = *(const f32x4*)(bhh + 512 + w * 32 + rq * 4);
  f32x4 bhn1 = *(const f32x4*)(bhh + 512 + w * 32 + 16 + rq * 4);

  const int myrow = b0 + cl;
  const int mylen = lens[myrow];
  const int* myseq = seqs + (size_t)myrow * Tt;
  const int vthr = Tt - mylen;

  for (int i = tid; i < 4096; i += 512) ((u32*)h_lds)[i] = 0;

  // lane LDS byte offsets (XOR-swizzled, verified in round 3)
  const int xk = (cl >> 1);
  const int rdoff = cl * 64 + (((rq + xk) & 3) << 4);            // + kb*1024
  const int wr0 = w * 1024 + cl * 64 + ((((rq >> 1) + xk) & 3) << 4) + (rq & 1) * 8;
  const int wr1 = w * 1024 + cl * 64 + ((((rq >> 1) + 2 + xk) & 3) << 4) + (rq & 1) * 8;

  const int colb0 = w * 32 + rq * 4;   // u16 offset of bi=0 gi chunk in a P row

  // ---- prologue: gi(0) into regs; token for step 1 ----
  u32x2 gi0[3], gi1[3];
  {
    const int tk = myseq[dir ? (Tt - 1) : 0];
    const int valid = dir ? (0 < mylen) : (0 >= vthr);
    const u32 off = (valid ? (u32)tk : (u32)Vv) * (u32)(Gg * 2);
    const u16* pr = (const u16*)((const char*)P + off) + colb0;
#pragma unroll
    for (int g = 0; g < 3; ++g) {
      gi0[g] = *(const u32x2*)(pr + g * 256);
      gi1[g] = *(const u32x2*)(pr + g * 256 + 16);
    }
  }
  int tok1 = myseq[dir ? (Tt - 2) : 1];
  block_sync_lds();

  int bb = 0;
#pragma unroll 1
  for (int s = 0; s < Tt; ++s) {
    const char* hb = (const char*)h_lds + bb;
    char* hn = (char*)h_lds + (bb ^ 8192);

    // ---- MFMA phase: no VMEM dependencies at all ----
    f32x4 zero4 = {0.f, 0.f, 0.f, 0.f};
    f32x4 ar0 = zero4, az0 = zero4, ar1 = zero4, az1 = zero4;
    f32x4 an0 = bhn0;                 // b_hh_n folded into acc init (registers)
    f32x4 an1 = bhn1;
#pragma unroll
    for (int kb = 0; kb < 8; ++kb) {
      const bf16x8 hf = *(const bf16x8*)(hb + kb * 1024 + rdoff);
      ar0 = __builtin_amdgcn_mfma_f32_16x16x32_bf16(wfrag[0][0][kb], hf, ar0, 0, 0, 0);
      az0 = __builtin_amdgcn_mfma_f32_16x16x32_bf16(wfrag[1][0][kb], hf, az0, 0, 0, 0);
      an0 = __builtin_amdgcn_mfma_f32_16x16x32_bf16(wfrag[2][0][kb], hf, an0, 0, 0, 0);
      ar1 = __builtin_amdgcn_mfma_f32_16x16x32_bf16(wfrag[0][1][kb], hf, ar1, 0, 0, 0);
      az1 = __builtin_amdgcn_mfma_f32_16x16x32_bf16(wfrag[1][1][kb], hf, az1, 0, 0, 0);
      an1 = __builtin_amdgcn_mfma_f32_16x16x32_bf16(wfrag[2][1][kb], hf, an1, 0, 0, 0);
    }

    // h(s) re-read for the z*(h-n) term (this lane's own last write, LDS)
    const u32x2 hp0 = *(const u32x2*)(hb + wr0);
    const u32x2 hp1 = *(const u32x2*)(hb + wr1);

    // token for s+2 (issued before GATES; 2-step prefetch distance)
    int tok2 = tok1;
    if (s + 2 < Tt) tok2 = myseq[dir ? (Tt - 3 - s) : (s + 2)];

    // gi row pointer for s+1
    const int validn = dir ? (s + 1 < mylen) : (s + 1 >= vthr);
    const u32 offn = (validn ? (u32)tok1 : (u32)Vv) * (u32)(Gg * 2);
    const u16* prn = (const u16*)((const char*)P + offn) + colb0;

    // ---- GATES (vmcnt wait on gi happens here) ----
#define GATES(GIS, AR, AZ, AN, HP, WRO, PRADD)                                   \
    {                                                                            \
      float hq[4];                                                               \
      const float hpv[4] = { bflo(HP[0]), bfhi(HP[0]), bflo(HP[1]), bfhi(HP[1]) };\
      _Pragma("unroll")                                                          \
      for (int q = 0; q < 4; ++q) {                                              \
        const u32 wr_ = (q & 2) ? GIS[0][1] : GIS[0][0];                         \
        const u32 wz_ = (q & 2) ? GIS[1][1] : GIS[1][0];                         \
        const u32 wn_ = (q & 2) ? GIS[2][1] : GIS[2][0];                         \
        const float ir = (q & 1) ? bfhi(wr_) : bflo(wr_);                        \
        const float iz = (q & 1) ? bfhi(wz_) : bflo(wz_);                        \
        const float in_ = (q & 1) ? bfhi(wn_) : bflo(wn_);                       \
        const float r = sigm(ir + AR[q]);                                        \
        const float z = sigm(iz + AZ[q]);                                        \
        const float n = tanh_fast(fmaf(r, AN[q], in_));                          \
        hq[q] = fmaf(z, hpv[q] - n, n);                                          \
      }                                                                          \
      u32 p0, p1;                                                                \
      asm("v_cvt_pk_bf16_f32 %0, %1, %2" : "=v"(p0) : "v"(hq[0]), "v"(hq[1]));   \
      asm("v_cvt_pk_bf16_f32 %0, %1, %2" : "=v"(p1) : "v"(hq[2]), "v"(hq[3]));   \
      u32x2 hw = {p0, p1};                                                       \
      *(u32x2*)(hn + WRO) = hw;                                                  \
      _Pragma("unroll")                                                          \
      for (int g = 0; g < 3; ++g) GIS[g] = *(const u32x2*)(prn + g * 256 + PRADD); \
    }

    GATES(gi0, ar0, az0, an0, hp0, wr0, 0)
    GATES(gi1, ar1, az1, an1, hp1, wr1, 16)
#undef GATES

    tok1 = tok2;
    bb ^= 8192;
    block_sync_lds();
  }

  // ---- final h (in LDS buffer 0 at this lane's write slots) -> rep ----
  {
    const char* hf_ = (const char*)h_lds;     // Tt even -> final buffer is 0
    const u32x2 f0 = *(const u32x2*)(hf_ + wr0);
    const u32x2 f1 = *(const u32x2*)(hf_ + wr1);
    float* rp = rep + (size_t)(b0 + cl) * (2 * Hh) + dir * Hh + w * 32 + rq * 4;
    rp[0] = bflo(f0[0]); rp[1] = bfhi(f0[0]); rp[2] = bflo(f0[1]); rp[3] = bfhi(f0[1]);
    rp[16] = bflo(f1[0]); rp[17] = bfhi(f1[0]); rp[18] = bflo(f1[1]); rp[19] = bfhi(f1[1]);
  }
}

// ---------------- K3a: h1 = relu(rep @ W1^T + b1) ----------------
__global__ __launch_bounds__(256) void k3a(
    const float* __restrict__ rep, const float* __restrict__ W1,
    const float* __restrict__ b1, float* __restrict__ h1)
{
  __shared__ float rl[512];
  const int b = blockIdx.x, t = threadIdx.x;
  rl[t] = rep[(size_t)b * 512 + t];
  rl[t + 256] = rep[(size_t)b * 512 + 256 + t];
  __syncthreads();
#pragma unroll
  for (int oo = 0; oo < 2; ++oo) {
    const int o = t + oo * 256;
    const float4* wr = (const float4*)(W1 + (size_t)o * 512);
    const float4* rr = (const float4*)rl;
    float acc = 0.f;
#pragma unroll 8
    for (int k = 0; k < 128; ++k) {
      const float4 wv = wr[k], rv = rr[k];
      acc += wv.x * rv.x + wv.y * rv.y + wv.z * rv.z + wv.w * rv.w;
    }
    h1[(size_t)b * 512 + o] = fmaxf(acc + b1[o], 0.f);
  }
}

// ---------------- K3b: out = softmax(h1 @ W2^T + b2) ----------------
__global__ __launch_bounds__(320) void k3b(
    const float* __restrict__ h1, const float* __restrict__ W2,
    const float* __restrict__ b2, float* __restrict__ out)
{
  __shared__ float lg[64 * 5];
  const int t = threadIdx.x;      // 320 = 5 classes x 64 batch
  const int c = t >> 6, b = t & 63;
  const float4* hr = (const float4*)(h1 + (size_t)b * 512);
  const float4* wr = (const float4*)(W2 + (size_t)c * 512);
  float acc = 0.f;
#pragma unroll 8
  for (int k = 0; k < 128; ++k) {
    const float4 hv = hr[k], wv = wr[k];
    acc += hv.x * wv.x + hv.y * wv.y + hv.z * wv.z + hv.w * wv.w;
  }
  lg[b * 5 + c] = acc + b2[c];
  __syncthreads();
  if (t < 64) {
    float v[5];
#pragma unroll
    for (int i = 0; i < 5; ++i) v[i] = lg[t * 5 + i];
    float m = v[0];
#pragma unroll
    for (int i = 1; i < 5; ++i) m = fmaxf(m, v[i]);
    float ssum = 0.f;
#pragma unroll
    for (int i = 0; i < 5; ++i) {
      v[i] = __builtin_amdgcn_exp2f(1.44269504089f * (v[i] - m));
      ssum += v[i];
    }
    const float inv = 1.0f / ssum;
#pragma unroll
    for (int i = 0; i < 5; ++i) out[t * 5 + i] = v[i] * inv;
  }
}

extern "C" void kernel_launch(void* const* d_in, const int* in_sizes, int n_in,
                              void* d_out, int out_size, void* d_ws, size_t ws_size,
                              hipStream_t stream) {
  const int* seqs = (const int*)d_in[0];
  const int* lens = (const int*)d_in[1];
  const float* emb = (const float*)d_in[2];
  const float* Wih_f = (const float*)d_in[3];
  const float* Whh_f = (const float*)d_in[4];
  const float* bih_f = (const float*)d_in[5];
  const float* bhh_f = (const float*)d_in[6];
  const float* Wih_b = (const float*)d_in[7];
  const float* Whh_b = (const float*)d_in[8];
  const float* bih_b = (const float*)d_in[9];
  const float* bhh_b = (const float*)d_in[10];
  const float* W1 = (const float*)d_in[11];
  const float* b1 = (const float*)d_in[12];
  const float* W2 = (const float*)d_in[13];
  const float* b2 = (const float*)d_in[14];
  float* out = (float*)d_out;

  char* ws = (char*)d_ws;
  const size_t PSZ = (size_t)(Vv + 1) * Gg * 2;   // 76,801,536 B per direction
  u16* Pf = (u16*)ws;
  u16* Pb = (u16*)(ws + PSZ);
  float* rep = (float*)(ws + 2 * PSZ);
  float* h1 = (float*)(ws + 2 * PSZ + 131072);

  hipLaunchKernelGGL(k0_bias, dim3(3), dim3(256), 0, stream,
                     bih_f, bhh_f, bih_b, bhh_b, Pf, Pb);
  hipLaunchKernelGGL(k1_proj, dim3(391, 2, 2), dim3(256), 0, stream,
                     emb, Wih_f, Wih_b, bih_f, bhh_f, bih_b, bhh_b, Pf, Pb);
  hipLaunchKernelGGL(k2_rec, dim3(8), dim3(512), 0, stream,
                     seqs, lens, Whh_f, Whh_b, bhh_f, bhh_b, Pf, Pb, rep);
  hipLaunchKernelGGL(k3a, dim3(64), dim3(256), 0, stream, rep, W1, b1, h1);
  hipLaunchKernelGGL(k3b, dim3(1), dim3(320), 0, stream, h1, W2, b2, out);
}